// Round 24
// baseline (462.921 us; speedup 1.0000x reference)
//
#include <hip/hip_runtime.h>
#include <hip/hip_bf16.h>

#define NN 100000
#define NE 800000
#define NR 3
#define F 128
#define M3 (NR * NN)               // 300000 CSR rows across relations
#define E3 (NR * NE)               // 2400000 edges total
#define NB1 ((M3 + 255) / 256)     // scan blocks
#define BPM (36 * 512)             // Bpack shorts per matrix (9 col-tiles x 4 k-tiles x 512)
#define GR 64                      // gemm rows per block

typedef __bf16 bf16x8 __attribute__((ext_vector_type(8)));
typedef float f32x4 __attribute__((ext_vector_type(4)));
typedef float f32x2 __attribute__((ext_vector_type(2)));

__device__ __forceinline__ float lrelu(float v) { return v >= 0.f ? v : 0.2f * v; }
__device__ __forceinline__ unsigned short f2bf(float f) {
    __hip_bfloat16 h = __float2bfloat16(f);
    unsigned short u;
    __builtin_memcpy(&u, &h, 2);
    return u;
}
// fp8 e4m3 helpers (gfx950 HW converters)
__device__ __forceinline__ f32x2 fp8x2_to_f32(unsigned short u) {
    return __builtin_amdgcn_cvt_pk_f32_fp8((int)u, false);
}
__device__ __forceinline__ unsigned pack4_fp8(float a, float b, float c, float d) {
    unsigned lo = __builtin_amdgcn_cvt_pk_fp8_f32(a, b, 0, false);
    return __builtin_amdgcn_cvt_pk_fp8_f32(c, d, lo, true);
}

// ---------------- device bodies (shared by fused kernels) ----------------
__device__ __forceinline__ void hist_body(int i, const int* __restrict__ edst,
                                          int* __restrict__ counts,
                                          int* __restrict__ eoff) {
    if (i >= E3) return;
    int r = i / NE;
    eoff[i] = atomicAdd(&counts[r * NN + edst[i]], 1);
}

// atomic-free single-pass scatter: slot = row_ptr[bucket] + eoff[i]
__device__ __forceinline__ void scatter_body(int i, const int* __restrict__ esrc,
                                             const int* __restrict__ edst,
                                             const int* __restrict__ row_ptr,
                                             const int* __restrict__ eoff,
                                             int* __restrict__ csr_src) {
    if (i >= E3) return;
    int d = edst[i];
    int r = i / NE;
    csr_src[row_ptr[r * NN + d] + eoff[i]] = esrc[i];
}

__device__ __forceinline__ void packW_body(int idx, const float* __restrict__ W1,
                                           const float* __restrict__ W2,
                                           const float* __restrict__ al1,
                                           const float* __restrict__ ar1,
                                           const float* __restrict__ al2,
                                           const float* __restrict__ ar2,
                                           unsigned short* __restrict__ Bp) {
    if (idx >= 6 * BPM) return;
    int j = idx & 7;
    int l = (idx >> 3) & 63;
    int tile = (idx >> 9) % 36;
    int m = idx / BPM;
    int ct = tile >> 2, kk = tile & 3;
    int k = kk * 32 + (l >> 4) * 8 + j;
    const float* W = (m < 3) ? (W1 + (size_t)m * (F * F)) : (W2 + (size_t)(m - 3) * (F * F));
    float v = 0.f;
    if (ct < 8) {
        int col = ct * 16 + (l & 15);
        v = W[k * F + col];
    } else {
        int cc = l & 15;
        int Hm = (m < 3) ? 4 : 1;
        int Dm = F / Hm;
        const float* alm = (m < 3) ? (al1 + m * F) : (al2 + (m - 3) * F);
        const float* arm = (m < 3) ? (ar1 + m * F) : (ar2 + (m - 3) * F);
        if (cc < Hm) {
            for (int d = 0; d < Dm; ++d) v += W[k * F + cc * Dm + d] * alm[cc * Dm + d];
        } else if (cc >= 4 && cc < 4 + Hm) {
            int h = cc - 4;
            for (int d = 0; d < Dm; ++d) v += W[k * F + h * Dm + d] * arm[h * Dm + d];
        }
    }
    Bp[idx] = f2bf(v);
}

// fused MFMA GEMM body: 64-row tile, double-buffered transposed-LDS epilogue
template <int H>
__device__ __forceinline__ void gemm_body(int bx, int t, const float* __restrict__ A,
                                          const unsigned short* __restrict__ Bp,
                                          unsigned char* __restrict__ Y,
                                          float* __restrict__ el,
                                          float* __restrict__ er) {
    __shared__ __align__(16) unsigned short alds[GR * 128];    // 16 KB, XOR-swizzled bf16
    __shared__ __align__(16) unsigned char olds[2][GR * 144];  // 2 x 9 KB, transposed fp8 out
    const int row0 = bx * GR;
    // stage A fp32 -> bf16 LDS (64 rows x 32 float4 granules = 2048)
#pragma unroll
    for (int it = 0; it < 8; ++it) {
        int g = it * 256 + t;
        int row = g >> 5, k4 = g & 31;
        int gr = row0 + row;
        float4 v;
        if (gr < NN) v = *(const float4*)(A + (size_t)gr * F + k4 * 4);
        else v = make_float4(0.f, 0.f, 0.f, 0.f);
        unsigned int lo = (unsigned)f2bf(v.x) | ((unsigned)f2bf(v.y) << 16);
        unsigned int hi = (unsigned)f2bf(v.z) | ((unsigned)f2bf(v.w) << 16);
        int k2 = k4 * 8;
        int byte = row * 256 + ((k2 & ~15) ^ ((row & 7) << 4)) + (k2 & 15);
        *(uint2*)((char*)alds + byte) = make_uint2(lo, hi);
    }
    __syncthreads();

    const int wv = t >> 6, lane = t & 63;
    const int lr = lane & 15;
    const int lkq = lane >> 4;
    const int n = row0 + wv * 16 + lr;   // this lane's node for epilogue
    for (int m = 0; m < NR; ++m) {
        unsigned char* ob = olds[m & 1];
        const bf16x8* bp = (const bf16x8*)(Bp + (size_t)m * BPM);
        f32x4 acc[8];
        f32x4 accE = (f32x4){0.f, 0.f, 0.f, 0.f};
#pragma unroll
        for (int ct = 0; ct < 8; ++ct) acc[ct] = (f32x4){0.f, 0.f, 0.f, 0.f};
#pragma unroll
        for (int kk = 0; kk < 4; ++kk) {
            int row = wv * 16 + lr;
            int k2 = kk * 64 + lkq * 16;
            int byte = row * 256 + (k2 ^ ((row & 7) << 4));
            bf16x8 afr = *(const bf16x8*)((const char*)alds + byte);
#pragma unroll
            for (int ct = 0; ct < 8; ++ct) {
                bf16x8 b = bp[(ct * 4 + kk) * 64 + lane];
                acc[ct] = __builtin_amdgcn_mfma_f32_16x16x32_bf16(b, afr, acc[ct], 0, 0, 0);
            }
            bf16x8 bE = bp[(32 + kk) * 64 + lane];
            accE = __builtin_amdgcn_mfma_f32_16x16x32_bf16(bE, afr, accE, 0, 0, 0);
        }
        // transposed epilogue: pk-u32 into padded LDS buffer (m&1), one barrier
#pragma unroll
        for (int ct = 0; ct < 8; ++ct) {
            unsigned pk = pack4_fp8(acc[ct][0], acc[ct][1], acc[ct][2], acc[ct][3]);
            *(unsigned*)(ob + (wv * 16 + lr) * 144 + ct * 16 + lkq * 4) = pk;
        }
        __syncthreads();   // ob ready; also guards alds reuse and prev-buffer drain
        unsigned char* Yp = Y + (size_t)m * NN * F;
#pragma unroll
        for (int it2 = 0; it2 < 2; ++it2) {
            int c = it2 * 256 + t;        // 512 chunks of 16 B
            int row = c >> 3, cc = c & 7;
            int gr = row0 + row;
            if (gr < NN)
                *(uint4*)(Yp + (size_t)gr * F + cc * 16) =
                    *(const uint4*)(ob + row * 144 + cc * 16);
        }
        // el/er (aug tile): lkq==0 -> el, lkq==1 -> er
        float* elp = el + (size_t)m * NN * H;
        float* erp = er + (size_t)m * NN * H;
        if (n < NN) {
            if (H == 4) {
                if (lkq == 0)
                    *(float4*)&elp[(size_t)n * 4] = make_float4(accE[0], accE[1], accE[2], accE[3]);
                else if (lkq == 1)
                    *(float4*)&erp[(size_t)n * 4] = make_float4(accE[0], accE[1], accE[2], accE[3]);
            } else {
                if (lkq == 0) elp[n] = accE[0];
                else if (lkq == 1) erp[n] = accE[0];
            }
        }
        // next relation writes the OTHER olds buffer; its barrier orders ours
    }
}

// ---------------- fused launch kernels ----------------
__global__ __launch_bounds__(256) void packw_hist_kernel(const float* __restrict__ W1,
                                                         const float* __restrict__ W2,
                                                         const float* __restrict__ al1,
                                                         const float* __restrict__ ar1,
                                                         const float* __restrict__ al2,
                                                         const float* __restrict__ ar2,
                                                         unsigned short* __restrict__ Bp,
                                                         const int* __restrict__ edst,
                                                         int* __restrict__ counts,
                                                         int* __restrict__ eoff,
                                                         int pw_grid) {
    if ((int)blockIdx.x < pw_grid)
        packW_body(blockIdx.x * 256 + threadIdx.x, W1, W2, al1, ar1, al2, ar2, Bp);
    else
        hist_body((blockIdx.x - pw_grid) * 256 + threadIdx.x, edst, counts, eoff);
}

// layer-1 GEMM overlapped with the single scatter pass (independent work)
template <int H>
__global__ __launch_bounds__(256) void gemm_scatter_kernel(const float* __restrict__ A,
                                                           const unsigned short* __restrict__ Bp,
                                                           unsigned char* __restrict__ Y,
                                                           float* __restrict__ el,
                                                           float* __restrict__ er,
                                                           const int* __restrict__ esrc,
                                                           const int* __restrict__ edst,
                                                           const int* __restrict__ row_ptr,
                                                           const int* __restrict__ eoff,
                                                           int* __restrict__ csr_src,
                                                           int gemm_grid) {
    if ((int)blockIdx.x < gemm_grid) {
        gemm_body<H>(blockIdx.x, threadIdx.x, A, Bp, Y, el, er);
    } else {
        int i = (blockIdx.x - gemm_grid) * 256 + threadIdx.x;
        scatter_body(i, esrc, edst, row_ptr, eoff, csr_src);
    }
}

// ---------------- scans ----------------
__global__ __launch_bounds__(256) void scan1_kernel(int* __restrict__ data,
                                                    int* __restrict__ bsum, int n) {
    __shared__ int lds[256];
    int i = blockIdx.x * 256 + threadIdx.x;
    int v = (i < n) ? data[i] : 0;
    lds[threadIdx.x] = v;
    __syncthreads();
#pragma unroll
    for (int off = 1; off < 256; off <<= 1) {
        int t = (threadIdx.x >= off) ? lds[threadIdx.x - off] : 0;
        __syncthreads();
        lds[threadIdx.x] += t;
        __syncthreads();
    }
    int incl = lds[threadIdx.x];
    if (i < n) data[i] = incl - v;
    if (threadIdx.x == 255) bsum[blockIdx.x] = incl;
}

__global__ __launch_bounds__(256) void scan2_kernel(int* __restrict__ bsum, int nb) {
    __shared__ int lds[256];
    int carry = 0;
    for (int base = 0; base < nb; base += 256) {
        int i = base + threadIdx.x;
        int v = (i < nb) ? bsum[i] : 0;
        lds[threadIdx.x] = v;
        __syncthreads();
#pragma unroll
        for (int off = 1; off < 256; off <<= 1) {
            int t = (threadIdx.x >= off) ? lds[threadIdx.x - off] : 0;
            __syncthreads();
            lds[threadIdx.x] += t;
            __syncthreads();
        }
        if (i < nb) bsum[i] = (lds[threadIdx.x] - v) + carry;
        int tot = lds[255];
        __syncthreads();
        carry += tot;
    }
}

__global__ __launch_bounds__(256) void scan3_kernel(int* __restrict__ row_ptr,
                                                    const int* __restrict__ bsum, int n) {
    int i = blockIdx.x * 256 + threadIdx.x;
    if (i >= n) return;
    row_ptr[i] += bsum[blockIdx.x];
}

// ---------------- wave-cooperative aggregation: half-wave per edge ----------
// (round-20 proven version: 4 gathers in flight per lane per 8-edge batch)
template <int H, int FIN>
__global__ __launch_bounds__(256) void aggr3_kernel(const int* __restrict__ row_ptr,
                                                    const int* __restrict__ csr_src,
                                                    const float* __restrict__ el,
                                                    const float* __restrict__ er,
                                                    const unsigned char* __restrict__ featb,
                                                    const float* __restrict__ resid,
                                                    const float* __restrict__ bias,
                                                    float* __restrict__ outp) {
    const int gid = blockIdx.x * 256 + threadIdx.x;
    const int d = gid >> 6;
    const int lane = gid & 63;
    if (d >= NN) return;
    const int half = lane >> 5;
    const int fi = (lane & 31) * 4;                   // features [fi, fi+4)
    const int CH = (H == 4) ? 16 : 64;
    const int myh = (H == 4) ? (fi >> 5) : 0;         // consumer head
    const int ph = (H == 4) ? (lane >> 4) : 0;        // producer head
    const int sub = lane & (CH - 1);                  // producer edge slot
    const int grpbase = (H == 4) ? myh * 16 : 0;      // shfl source base
    float a0 = 0.f, a1 = 0.f, a2 = 0.f, a3 = 0.f;
    for (int r = 0; r < NR; ++r) {
        const int idx = r * NN + d;
        const int rs = row_ptr[idx];
        const int re = (idx + 1 < M3) ? row_ptr[idx + 1] : E3;
        const float erh = er[(size_t)r * NN * H + d * H + ph];
        const float* elr = el + (size_t)r * NN * H;
        const unsigned char* fb = featb + (size_t)r * NN * F;
        float den = 0.f, b0 = 0.f, b1 = 0.f, b2 = 0.f, b3 = 0.f;
        for (int base = rs; base < re; base += CH) {
            int cnt = re - base;
            if (cnt > CH) cnt = CH;
            int s_l = 0;
            float w_l = 0.f;
            if (sub < cnt) {
                s_l = csr_src[base + sub];
                w_l = __expf(lrelu(elr[s_l * H + ph] + erh));
            }
            den += w_l;
            for (int j = 0; j < cnt; j += 8) {        // 8 edges/batch: 4 per half
                int sj[4];
                float wj[4];
#pragma unroll
                for (int q = 0; q < 4; ++q) {
                    int e = j + 2 * q + half;
                    int ec = e < cnt ? e : cnt - 1;   // wave-uniform-bound clamp
                    sj[q] = __shfl(s_l, grpbase + ec);
                    float w = __shfl(w_l, grpbase + ec);
                    wj[q] = (e < cnt) ? w : 0.f;
                }
                unsigned u[4];
#pragma unroll
                for (int q = 0; q < 4; ++q)
                    u[q] = *(const unsigned*)(fb + (size_t)sj[q] * F + fi);
#pragma unroll
                for (int q = 0; q < 4; ++q) {
                    f32x2 d0 = fp8x2_to_f32((unsigned short)(u[q] & 0xffff));
                    f32x2 d1 = fp8x2_to_f32((unsigned short)(u[q] >> 16));
                    b0 += wj[q] * d0.x;
                    b1 += wj[q] * d0.y;
                    b2 += wj[q] * d1.x;
                    b3 += wj[q] * d1.y;
                }
            }
        }
#pragma unroll
        for (int off = CH >> 1; off; off >>= 1) den += __shfl_xor(den, off);
        float dh = (H == 4) ? __shfl(den, grpbase) : den;
        float rd = 1.f / fmaxf(dh, 1e-9f);
        a0 += b0 * rd;
        a1 += b1 * rd;
        a2 += b2 * rd;
        a3 += b3 * rd;
    }
    a0 += __shfl_xor(a0, 32);
    a1 += __shfl_xor(a1, 32);
    a2 += __shfl_xor(a2, 32);
    a3 += __shfl_xor(a3, 32);
    if (half == 0) {
        const float third = 1.f / 3.f;
        size_t o = (size_t)d * F + fi;
        float4 bA = *(const float4*)&bias[fi];
        float4 bB = *(const float4*)&bias[F + fi];
        float4 bC = *(const float4*)&bias[2 * F + fi];
        float4 rv = *(const float4*)&resid[o];
        float v0 = a0 * third + rv.x + (bA.x + bB.x + bC.x) * third;
        float v1 = a1 * third + rv.y + (bA.y + bB.y + bC.y) * third;
        float v2 = a2 * third + rv.z + (bA.z + bB.z + bC.z) * third;
        float v3 = a3 * third + rv.w + (bA.w + bB.w + bC.w) * third;
        if (FIN == 1) {
            v0 = v0 > 0.f ? v0 : (__expf(v0) - 1.f);
            v1 = v1 > 0.f ? v1 : (__expf(v1) - 1.f);
            v2 = v2 > 0.f ? v2 : (__expf(v2) - 1.f);
            v3 = v3 > 0.f ? v3 : (__expf(v3) - 1.f);
        }
        *(float4*)&outp[o] = make_float4(v0, v1, v2, v3);
    }
}

extern "C" void kernel_launch(void* const* d_in, const int* in_sizes, int n_in,
                              void* d_out, int out_size, void* d_ws, size_t ws_size,
                              hipStream_t stream) {
    const float* x   = (const float*)d_in[0];
    const int* esrc  = (const int*)d_in[1];
    const int* edst  = (const int*)d_in[2];
    const float* W1  = (const float*)d_in[3];
    const float* b1  = (const float*)d_in[4];
    const float* al1 = (const float*)d_in[5];
    const float* ar1 = (const float*)d_in[6];
    const float* W2  = (const float*)d_in[7];
    const float* b2  = (const float*)d_in[8];
    const float* al2 = (const float*)d_in[9];
    const float* ar2 = (const float*)d_in[10];
    float* out = (float*)d_out;

    // workspace (~69 MB; proven-safe >= 108.8 MB). h1 lives in d_out.
    char* p = (char*)d_ws;
    unsigned char* featb = (unsigned char*)p;    p += (size_t)NR * NN * F;      // 38.4 MB
    float* el    = (float*)p;                    p += (size_t)NR * NN * 4 * 4;  // 4.8 MB
    float* er    = (float*)p;                    p += (size_t)NR * NN * 4 * 4;
    int* row_ptr = (int*)p;                      p += (size_t)M3 * 4;           // 1.2 MB
    int* bsum    = (int*)p;                      p += (size_t)((NB1 + 63) & ~63) * 4;
    int* csr_src = (int*)p;                      p += (size_t)E3 * 4;           // 9.6 MB
    int* eoff    = (int*)p;                      p += (size_t)E3 * 4;           // 9.6 MB
    unsigned short* Bpack = (unsigned short*)p;  p += (size_t)6 * BPM * 2;      // 221 KB
    float* h1 = out;

    dim3 b256(256);
    const int eg3 = (E3 + 255) / 256;
    const int gemm_grid = (NN + GR - 1) / GR;
    const int agg = (NN * 64 + 255) / 256;
    const int pw_grid = (6 * BPM + 255) / 256;

    // ---- K0: zero counts
    hipMemsetAsync(row_ptr, 0, (size_t)M3 * 4, stream);
    // ---- K1: packW ∥ hist+eoff (independent)
    packw_hist_kernel<<<pw_grid + eg3, b256, 0, stream>>>(W1, W2, al1, ar1, al2, ar2, Bpack,
                                                          edst, row_ptr, eoff, pw_grid);
    // ---- K2..K4: scan (row_ptr := exclusive bucket starts)
    scan1_kernel<<<NB1, b256, 0, stream>>>(row_ptr, bsum, M3);
    scan2_kernel<<<1, b256, 0, stream>>>(bsum, NB1);
    scan3_kernel<<<NB1, b256, 0, stream>>>(row_ptr, bsum, M3);

    // ---- K5: layer-1 GEMM ∥ atomic-free single-pass scatter
    gemm_scatter_kernel<4><<<gemm_grid + eg3, b256, 0, stream>>>(
        x, Bpack, featb, el, er, esrc, edst, row_ptr, eoff, csr_src, gemm_grid);

    // ---- K6: layer-1 aggregation (mean, +res +bias, ELU) -> h1 in d_out
    aggr3_kernel<4, 1><<<agg, b256, 0, stream>>>(row_ptr, csr_src, el, er, featb, x, b1, h1);

    // ---- K7: layer-2 GEMM (no scatter part: grid = gemm_grid only)
    gemm_scatter_kernel<1><<<gemm_grid, b256, 0, stream>>>(
        h1, Bpack + (size_t)3 * BPM, featb, el, er, esrc, edst, row_ptr, eoff, csr_src,
        gemm_grid);

    // ---- K8: layer-2 aggregation (mean, +res +bias) -> out
    aggr3_kernel<1, 2><<<agg, b256, 0, stream>>>(row_ptr, csr_src, el, er, featb, h1, b2, out);
}

// Round 25
// 440.573 us; speedup vs baseline: 1.0507x; 1.0507x over previous
//
#include <hip/hip_runtime.h>
#include <hip/hip_bf16.h>

#define NN 100000
#define NE 800000
#define NR 3
#define F 128
#define M3 (NR * NN)               // 300000 CSR rows across relations
#define E3 (NR * NE)               // 2400000 edges total
#define NB1 ((M3 + 255) / 256)     // scan blocks
#define NPASS 2
#define PW ((NN + NPASS - 1) / NPASS)   // dst window per scatter pass
#define BPM (36 * 512)             // Bpack shorts per matrix (9 col-tiles x 4 k-tiles x 512)
#define GR 64                      // gemm rows per block

typedef __bf16 bf16x8 __attribute__((ext_vector_type(8)));
typedef float f32x4 __attribute__((ext_vector_type(4)));
typedef float f32x2 __attribute__((ext_vector_type(2)));

__device__ __forceinline__ float lrelu(float v) { return v >= 0.f ? v : 0.2f * v; }
__device__ __forceinline__ unsigned short f2bf(float f) {
    __hip_bfloat16 h = __float2bfloat16(f);
    unsigned short u;
    __builtin_memcpy(&u, &h, 2);
    return u;
}
// fp8 e4m3 helpers (gfx950 HW converters)
__device__ __forceinline__ f32x2 fp8x2_to_f32(unsigned short u) {
    return __builtin_amdgcn_cvt_pk_f32_fp8((int)u, false);
}
__device__ __forceinline__ unsigned pack4_fp8(float a, float b, float c, float d) {
    unsigned lo = __builtin_amdgcn_cvt_pk_fp8_f32(a, b, 0, false);
    return __builtin_amdgcn_cvt_pk_fp8_f32(c, d, lo, true);
}

// ---------------- device bodies (shared by fused kernels) ----------------
__device__ __forceinline__ void hist_body(int i, const int* __restrict__ edst,
                                          int* __restrict__ counts,
                                          int* __restrict__ eoff) {
    if (i >= E3) return;
    int r = i / NE;
    eoff[i] = atomicAdd(&counts[r * NN + edst[i]], 1);
}

__device__ __forceinline__ void scatter_body(int i, int lo, const int* __restrict__ esrc,
                                             const int* __restrict__ edst,
                                             const int* __restrict__ row_ptr,
                                             const int* __restrict__ eoff,
                                             int* __restrict__ csr_src) {
    if (i >= E3) return;
    int d = edst[i];
    if (d < lo || d >= lo + PW) return;
    int r = i / NE;
    csr_src[row_ptr[r * NN + d] + eoff[i]] = esrc[i];
}

__device__ __forceinline__ void packW_body(int idx, const float* __restrict__ W1,
                                           const float* __restrict__ W2,
                                           const float* __restrict__ al1,
                                           const float* __restrict__ ar1,
                                           const float* __restrict__ al2,
                                           const float* __restrict__ ar2,
                                           unsigned short* __restrict__ Bp) {
    if (idx >= 6 * BPM) return;
    int j = idx & 7;
    int l = (idx >> 3) & 63;
    int tile = (idx >> 9) % 36;
    int m = idx / BPM;
    int ct = tile >> 2, kk = tile & 3;
    int k = kk * 32 + (l >> 4) * 8 + j;
    const float* W = (m < 3) ? (W1 + (size_t)m * (F * F)) : (W2 + (size_t)(m - 3) * (F * F));
    float v = 0.f;
    if (ct < 8) {
        int col = ct * 16 + (l & 15);
        v = W[k * F + col];
    } else {
        int cc = l & 15;
        int Hm = (m < 3) ? 4 : 1;
        int Dm = F / Hm;
        const float* alm = (m < 3) ? (al1 + m * F) : (al2 + (m - 3) * F);
        const float* arm = (m < 3) ? (ar1 + m * F) : (ar2 + (m - 3) * F);
        if (cc < Hm) {
            for (int d = 0; d < Dm; ++d) v += W[k * F + cc * Dm + d] * alm[cc * Dm + d];
        } else if (cc >= 4 && cc < 4 + Hm) {
            int h = cc - 4;
            for (int d = 0; d < Dm; ++d) v += W[k * F + h * Dm + d] * arm[h * Dm + d];
        }
    }
    Bp[idx] = f2bf(v);
}

// fused MFMA GEMM body: 64-row tile, transposed-LDS coalesced fp8 stores
template <int H>
__device__ __forceinline__ void gemm_body(int bx, int t, const float* __restrict__ A,
                                          const unsigned short* __restrict__ Bp,
                                          unsigned char* __restrict__ Y,
                                          float* __restrict__ el,
                                          float* __restrict__ er) {
    __shared__ __align__(16) unsigned short alds[GR * 128];   // 16 KB, XOR-swizzled bf16
    __shared__ __align__(16) unsigned char olds[GR * 144];    // 9 KB, transposed fp8 out
    const int row0 = bx * GR;
    // stage A fp32 -> bf16 LDS (64 rows x 32 float4 granules = 2048)
#pragma unroll
    for (int it = 0; it < 8; ++it) {
        int g = it * 256 + t;
        int row = g >> 5, k4 = g & 31;
        int gr = row0 + row;
        float4 v;
        if (gr < NN) v = *(const float4*)(A + (size_t)gr * F + k4 * 4);
        else v = make_float4(0.f, 0.f, 0.f, 0.f);
        unsigned int lo = (unsigned)f2bf(v.x) | ((unsigned)f2bf(v.y) << 16);
        unsigned int hi = (unsigned)f2bf(v.z) | ((unsigned)f2bf(v.w) << 16);
        int k2 = k4 * 8;
        int byte = row * 256 + ((k2 & ~15) ^ ((row & 7) << 4)) + (k2 & 15);
        *(uint2*)((char*)alds + byte) = make_uint2(lo, hi);
    }
    __syncthreads();

    const int wv = t >> 6, lane = t & 63;
    const int lr = lane & 15;
    const int lkq = lane >> 4;
    const int n = row0 + wv * 16 + lr;   // this lane's node for epilogue
    for (int m = 0; m < NR; ++m) {
        const bf16x8* bp = (const bf16x8*)(Bp + (size_t)m * BPM);
        f32x4 acc[8];
        f32x4 accE = (f32x4){0.f, 0.f, 0.f, 0.f};
#pragma unroll
        for (int ct = 0; ct < 8; ++ct) acc[ct] = (f32x4){0.f, 0.f, 0.f, 0.f};
#pragma unroll
        for (int kk = 0; kk < 4; ++kk) {
            int row = wv * 16 + lr;
            int k2 = kk * 64 + lkq * 16;
            int byte = row * 256 + (k2 ^ ((row & 7) << 4));
            bf16x8 afr = *(const bf16x8*)((const char*)alds + byte);
#pragma unroll
            for (int ct = 0; ct < 8; ++ct) {
                bf16x8 b = bp[(ct * 4 + kk) * 64 + lane];
                acc[ct] = __builtin_amdgcn_mfma_f32_16x16x32_bf16(b, afr, acc[ct], 0, 0, 0);
            }
            bf16x8 bE = bp[(32 + kk) * 64 + lane];
            accE = __builtin_amdgcn_mfma_f32_16x16x32_bf16(bE, afr, accE, 0, 0, 0);
        }
        // transposed epilogue: pk-u32 into padded LDS, then coalesced row stores
#pragma unroll
        for (int ct = 0; ct < 8; ++ct) {
            unsigned pk = pack4_fp8(acc[ct][0], acc[ct][1], acc[ct][2], acc[ct][3]);
            *(unsigned*)(olds + (wv * 16 + lr) * 144 + ct * 16 + lkq * 4) = pk;
        }
        __syncthreads();
        unsigned char* Yp = Y + (size_t)m * NN * F;
#pragma unroll
        for (int it2 = 0; it2 < 2; ++it2) {
            int c = it2 * 256 + t;        // 512 chunks of 16 B
            int row = c >> 3, cc = c & 7;
            int gr = row0 + row;
            if (gr < NN)
                *(uint4*)(Yp + (size_t)gr * F + cc * 16) =
                    *(const uint4*)(olds + row * 144 + cc * 16);
        }
        // el/er (aug tile): lkq==0 -> el, lkq==1 -> er
        float* elp = el + (size_t)m * NN * H;
        float* erp = er + (size_t)m * NN * H;
        if (n < NN) {
            if (H == 4) {
                if (lkq == 0)
                    *(float4*)&elp[(size_t)n * 4] = make_float4(accE[0], accE[1], accE[2], accE[3]);
                else if (lkq == 1)
                    *(float4*)&erp[(size_t)n * 4] = make_float4(accE[0], accE[1], accE[2], accE[3]);
            } else {
                if (lkq == 0) elp[n] = accE[0];
                else if (lkq == 1) erp[n] = accE[0];
            }
        }
        __syncthreads();  // protect olds before next relation overwrites
    }
}

// ---------------- fused launch kernels ----------------
__global__ __launch_bounds__(256) void packw_hist_kernel(const float* __restrict__ W1,
                                                         const float* __restrict__ W2,
                                                         const float* __restrict__ al1,
                                                         const float* __restrict__ ar1,
                                                         const float* __restrict__ al2,
                                                         const float* __restrict__ ar2,
                                                         unsigned short* __restrict__ Bp,
                                                         const int* __restrict__ edst,
                                                         int* __restrict__ counts,
                                                         int* __restrict__ eoff,
                                                         int pw_grid) {
    if ((int)blockIdx.x < pw_grid)
        packW_body(blockIdx.x * 256 + threadIdx.x, W1, W2, al1, ar1, al2, ar2, Bp);
    else
        hist_body((blockIdx.x - pw_grid) * 256 + threadIdx.x, edst, counts, eoff);
}

template <int H>
__global__ __launch_bounds__(256) void gemm_scatter_kernel(const float* __restrict__ A,
                                                           const unsigned short* __restrict__ Bp,
                                                           unsigned char* __restrict__ Y,
                                                           float* __restrict__ el,
                                                           float* __restrict__ er,
                                                           const int* __restrict__ esrc,
                                                           const int* __restrict__ edst,
                                                           const int* __restrict__ row_ptr,
                                                           const int* __restrict__ eoff,
                                                           int* __restrict__ csr_src,
                                                           int gemm_grid, int eg3) {
    if ((int)blockIdx.x < gemm_grid) {
        gemm_body<H>(blockIdx.x, threadIdx.x, A, Bp, Y, el, er);
    } else {
        int b = blockIdx.x - gemm_grid;
        int pass = b / eg3;
        int i = (b - pass * eg3) * 256 + threadIdx.x;
        scatter_body(i, pass * PW, esrc, edst, row_ptr, eoff, csr_src);
    }
}

// ---------------- scans ----------------
__global__ __launch_bounds__(256) void scan1_kernel(int* __restrict__ data,
                                                    int* __restrict__ bsum, int n) {
    __shared__ int lds[256];
    int i = blockIdx.x * 256 + threadIdx.x;
    int v = (i < n) ? data[i] : 0;
    lds[threadIdx.x] = v;
    __syncthreads();
#pragma unroll
    for (int off = 1; off < 256; off <<= 1) {
        int t = (threadIdx.x >= off) ? lds[threadIdx.x - off] : 0;
        __syncthreads();
        lds[threadIdx.x] += t;
        __syncthreads();
    }
    int incl = lds[threadIdx.x];
    if (i < n) data[i] = incl - v;
    if (threadIdx.x == 255) bsum[blockIdx.x] = incl;
}

__global__ __launch_bounds__(256) void scan2_kernel(int* __restrict__ bsum, int nb) {
    __shared__ int lds[256];
    int carry = 0;
    for (int base = 0; base < nb; base += 256) {
        int i = base + threadIdx.x;
        int v = (i < nb) ? bsum[i] : 0;
        lds[threadIdx.x] = v;
        __syncthreads();
#pragma unroll
        for (int off = 1; off < 256; off <<= 1) {
            int t = (threadIdx.x >= off) ? lds[threadIdx.x - off] : 0;
            __syncthreads();
            lds[threadIdx.x] += t;
            __syncthreads();
        }
        if (i < nb) bsum[i] = (lds[threadIdx.x] - v) + carry;
        int tot = lds[255];
        __syncthreads();
        carry += tot;
    }
}

__global__ __launch_bounds__(256) void scan3_kernel(int* __restrict__ row_ptr,
                                                    const int* __restrict__ bsum, int n) {
    int i = blockIdx.x * 256 + threadIdx.x;
    if (i >= n) return;
    row_ptr[i] += bsum[blockIdx.x];
}

// ---------------- wave-cooperative aggregation: half-wave per edge ----------
// (round-20 proven version: 4 gathers in flight per lane per 8-edge batch)
template <int H, int FIN>
__global__ __launch_bounds__(256) void aggr3_kernel(const int* __restrict__ row_ptr,
                                                    const int* __restrict__ csr_src,
                                                    const float* __restrict__ el,
                                                    const float* __restrict__ er,
                                                    const unsigned char* __restrict__ featb,
                                                    const float* __restrict__ resid,
                                                    const float* __restrict__ bias,
                                                    float* __restrict__ outp) {
    const int gid = blockIdx.x * 256 + threadIdx.x;
    const int d = gid >> 6;
    const int lane = gid & 63;
    if (d >= NN) return;
    const int half = lane >> 5;
    const int fi = (lane & 31) * 4;                   // features [fi, fi+4)
    const int CH = (H == 4) ? 16 : 64;
    const int myh = (H == 4) ? (fi >> 5) : 0;         // consumer head
    const int ph = (H == 4) ? (lane >> 4) : 0;        // producer head
    const int sub = lane & (CH - 1);                  // producer edge slot
    const int grpbase = (H == 4) ? myh * 16 : 0;      // shfl source base
    float a0 = 0.f, a1 = 0.f, a2 = 0.f, a3 = 0.f;
    for (int r = 0; r < NR; ++r) {
        const int idx = r * NN + d;
        const int rs = row_ptr[idx];
        const int re = (idx + 1 < M3) ? row_ptr[idx + 1] : E3;
        const float erh = er[(size_t)r * NN * H + d * H + ph];
        const float* elr = el + (size_t)r * NN * H;
        const unsigned char* fb = featb + (size_t)r * NN * F;
        float den = 0.f, b0 = 0.f, b1 = 0.f, b2 = 0.f, b3 = 0.f;
        for (int base = rs; base < re; base += CH) {
            int cnt = re - base;
            if (cnt > CH) cnt = CH;
            int s_l = 0;
            float w_l = 0.f;
            if (sub < cnt) {
                s_l = csr_src[base + sub];
                w_l = __expf(lrelu(elr[s_l * H + ph] + erh));
            }
            den += w_l;
            for (int j = 0; j < cnt; j += 8) {        // 8 edges/batch: 4 per half
                int sj[4];
                float wj[4];
#pragma unroll
                for (int q = 0; q < 4; ++q) {
                    int e = j + 2 * q + half;
                    int ec = e < cnt ? e : cnt - 1;   // wave-uniform-bound clamp
                    sj[q] = __shfl(s_l, grpbase + ec);
                    float w = __shfl(w_l, grpbase + ec);
                    wj[q] = (e < cnt) ? w : 0.f;
                }
                unsigned u[4];
#pragma unroll
                for (int q = 0; q < 4; ++q)
                    u[q] = *(const unsigned*)(fb + (size_t)sj[q] * F + fi);
#pragma unroll
                for (int q = 0; q < 4; ++q) {
                    f32x2 d0 = fp8x2_to_f32((unsigned short)(u[q] & 0xffff));
                    f32x2 d1 = fp8x2_to_f32((unsigned short)(u[q] >> 16));
                    b0 += wj[q] * d0.x;
                    b1 += wj[q] * d0.y;
                    b2 += wj[q] * d1.x;
                    b3 += wj[q] * d1.y;
                }
            }
        }
#pragma unroll
        for (int off = CH >> 1; off; off >>= 1) den += __shfl_xor(den, off);
        float dh = (H == 4) ? __shfl(den, grpbase) : den;
        float rd = 1.f / fmaxf(dh, 1e-9f);
        a0 += b0 * rd;
        a1 += b1 * rd;
        a2 += b2 * rd;
        a3 += b3 * rd;
    }
    a0 += __shfl_xor(a0, 32);
    a1 += __shfl_xor(a1, 32);
    a2 += __shfl_xor(a2, 32);
    a3 += __shfl_xor(a3, 32);
    if (half == 0) {
        const float third = 1.f / 3.f;
        size_t o = (size_t)d * F + fi;
        float4 bA = *(const float4*)&bias[fi];
        float4 bB = *(const float4*)&bias[F + fi];
        float4 bC = *(const float4*)&bias[2 * F + fi];
        float4 rv = *(const float4*)&resid[o];
        float v0 = a0 * third + rv.x + (bA.x + bB.x + bC.x) * third;
        float v1 = a1 * third + rv.y + (bA.y + bB.y + bC.y) * third;
        float v2 = a2 * third + rv.z + (bA.z + bB.z + bC.z) * third;
        float v3 = a3 * third + rv.w + (bA.w + bB.w + bC.w) * third;
        if (FIN == 1) {
            v0 = v0 > 0.f ? v0 : (__expf(v0) - 1.f);
            v1 = v1 > 0.f ? v1 : (__expf(v1) - 1.f);
            v2 = v2 > 0.f ? v2 : (__expf(v2) - 1.f);
            v3 = v3 > 0.f ? v3 : (__expf(v3) - 1.f);
        }
        *(float4*)&outp[o] = make_float4(v0, v1, v2, v3);
    }
}

extern "C" void kernel_launch(void* const* d_in, const int* in_sizes, int n_in,
                              void* d_out, int out_size, void* d_ws, size_t ws_size,
                              hipStream_t stream) {
    const float* x   = (const float*)d_in[0];
    const int* esrc  = (const int*)d_in[1];
    const int* edst  = (const int*)d_in[2];
    const float* W1  = (const float*)d_in[3];
    const float* b1  = (const float*)d_in[4];
    const float* al1 = (const float*)d_in[5];
    const float* ar1 = (const float*)d_in[6];
    const float* W2  = (const float*)d_in[7];
    const float* b2  = (const float*)d_in[8];
    const float* al2 = (const float*)d_in[9];
    const float* ar2 = (const float*)d_in[10];
    float* out = (float*)d_out;

    // workspace (~69 MB; proven-safe >= 108.8 MB). h1 lives in d_out.
    char* p = (char*)d_ws;
    unsigned char* featb = (unsigned char*)p;    p += (size_t)NR * NN * F;      // 38.4 MB
    float* el    = (float*)p;                    p += (size_t)NR * NN * 4 * 4;  // 4.8 MB
    float* er    = (float*)p;                    p += (size_t)NR * NN * 4 * 4;
    int* row_ptr = (int*)p;                      p += (size_t)M3 * 4;           // 1.2 MB
    int* bsum    = (int*)p;                      p += (size_t)((NB1 + 63) & ~63) * 4;
    int* csr_src = (int*)p;                      p += (size_t)E3 * 4;           // 9.6 MB
    int* eoff    = (int*)p;                      p += (size_t)E3 * 4;           // 9.6 MB
    unsigned short* Bpack = (unsigned short*)p;  p += (size_t)6 * BPM * 2;      // 221 KB
    float* h1 = out;

    dim3 b256(256);
    const int eg3 = (E3 + 255) / 256;
    const int gemm_grid = (NN + GR - 1) / GR;
    const int agg = (NN * 64 + 255) / 256;
    const int pw_grid = (6 * BPM + 255) / 256;

    // ---- K0: zero counts
    hipMemsetAsync(row_ptr, 0, (size_t)M3 * 4, stream);
    // ---- K1: packW ∥ hist+eoff (independent)
    packw_hist_kernel<<<pw_grid + eg3, b256, 0, stream>>>(W1, W2, al1, ar1, al2, ar2, Bpack,
                                                          edst, row_ptr, eoff, pw_grid);
    // ---- K2..K4: scan (row_ptr := exclusive bucket starts)
    scan1_kernel<<<NB1, b256, 0, stream>>>(row_ptr, bsum, M3);
    scan2_kernel<<<1, b256, 0, stream>>>(bsum, NB1);
    scan3_kernel<<<NB1, b256, 0, stream>>>(row_ptr, bsum, M3);

    // ---- K5: layer-1 GEMM ∥ atomic-free scatter x NPASS
    gemm_scatter_kernel<4><<<gemm_grid + NPASS * eg3, b256, 0, stream>>>(
        x, Bpack, featb, el, er, esrc, edst, row_ptr, eoff, csr_src, gemm_grid, eg3);

    // ---- K6: layer-1 aggregation (mean, +res +bias, ELU) -> h1 in d_out
    aggr3_kernel<4, 1><<<agg, b256, 0, stream>>>(row_ptr, csr_src, el, er, featb, x, b1, h1);

    // ---- K7: layer-2 GEMM (no scatter part: grid = gemm_grid only)
    gemm_scatter_kernel<1><<<gemm_grid, b256, 0, stream>>>(
        h1, Bpack + (size_t)3 * BPM, featb, el, er, esrc, edst, row_ptr, eoff, csr_src,
        gemm_grid, eg3);

    // ---- K8: layer-2 aggregation (mean, +res +bias) -> out
    aggr3_kernel<1, 2><<<agg, b256, 0, stream>>>(row_ptr, csr_src, el, er, featb, h1, b2, out);
}